// Round 4
// baseline (35450.101 us; speedup 1.0000x reference)
//
#include <hip/hip_runtime.h>

// TimeframeEncoder R4: weight-stationary across a 4-CU group.
// 64 blocks x 512 thr (8 waves, __launch_bounds__(512,2) -> 256 VGPR budget).
// Group g = blocks {g, g+16, g+32, g+48} (same XCD under %8 round-robin; only
// perf depends on that, correctness uses device-scope atomics). Group owns
// batch rows [16g,16g+16); block quarter bq owns output cols [64bq,64bq+64).
// Every wave pins 39 B-frag tiles (156 VGPR) via asm, identical count on all
// waves: z-waves (0-3) hold z-gate/candidate-half tiles, r-waves (4-7) hold
// r-gate/other-half tiles. 4 device-scope all-gathers per step (rh0,h0,rh1,h1).

#define HID 256
#define SEQL 512
#define IDIM 64

#define GATHER_BASE 1310720u              // bytes; weights end at 1,277,952
#define GRP_STRIDE  32768u                // 4 x 8 KB buffers per group
#define CTR_BASE    (GATHER_BASE + 16u * GRP_STRIDE)
#define CTR_PAD     16                    // ints per counter slot (64 B)

typedef __bf16 bf16x8 __attribute__((ext_vector_type(8)));
typedef float f32x4 __attribute__((ext_vector_type(4)));

__device__ __forceinline__ unsigned short f2bf(float f) {
  unsigned int u = __builtin_bit_cast(unsigned int, f);
  u += 0x7fffu + ((u >> 16) & 1u);
  return (unsigned short)(u >> 16);
}
__device__ __forceinline__ float bf2f(unsigned short u) {
  unsigned int v = ((unsigned int)u) << 16;
  return __builtin_bit_cast(float, v);
}
__device__ __forceinline__ float sigm(float x) { return 1.0f / (1.0f + __expf(-x)); }
__device__ __forceinline__ float tanh_(float x) { return 1.0f - 2.0f / (__expf(2.0f * x) + 1.0f); }
__device__ __forceinline__ float sanit(float v) {
  if (!(v == v)) return 0.f;
  if (isinf(v)) return v > 0.f ? 10.f : -10.f;
  return v;
}

// Weight prep (layout verified R1-R3): bf16 B-fragments, tile = 512 ushort.
// Wz0p tiles [0,320): (nt<32,kt<10); Wc0p base 320 (nt<16,kt<10);
// Wz1p base 480 (nt<32,kt<16); Wc1p base 992 (nt<16,kt<16).
__global__ __launch_bounds__(256) void prep_weights(
    const float* __restrict__ Wz0, const float* __restrict__ Wc0,
    const float* __restrict__ Wz1, const float* __restrict__ Wc1,
    unsigned short* __restrict__ ws) {
  int idx = blockIdx.x * 256 + threadIdx.x;  // 638976 threads
  const float* W;
  int stride, KT, base;
  if (idx < 163840)      { W = Wz0; stride = 768; KT = 10; base = 0; }
  else if (idx < 245760) { W = Wc0; stride = 256; KT = 10; base = 163840; idx -= 163840; }
  else if (idx < 507904) { W = Wz1; stride = 768; KT = 16; base = 245760; idx -= 245760; }
  else                   { W = Wc1; stride = 256; KT = 16; base = 507904; idx -= 507904; }
  int tile = idx >> 9;
  int t = idx & 511;
  int nt = tile / KT;
  int kt = tile - nt * KT;
  int n15 = t & 15;
  int klocal = t >> 4;
  int k = (kt << 5) + klocal;
  int n = (nt << 4) + n15;
  int lane = ((klocal >> 3) << 4) | n15;
  int j = klocal & 7;
  ws[base + (tile << 9) + (lane << 3) + j] = f2bf(W[k * stride + n]);
}

// release-fence, count in, spin for whole group, acquire-fence.
__device__ __forceinline__ void gsync(int* ctrp, int target, int tid) {
  __threadfence();
  __syncthreads();
  if (tid == 0) {
    __hip_atomic_fetch_add(ctrp, 1, __ATOMIC_RELEASE, __HIP_MEMORY_SCOPE_AGENT);
    int it = 0;
    while (__hip_atomic_load(ctrp, __ATOMIC_ACQUIRE, __HIP_MEMORY_SCOPE_AGENT) < target) {
      __builtin_amdgcn_s_sleep(2);
      if (++it > (1 << 27)) break;  // safety valve against true deadlock
    }
  }
  __syncthreads();
  __threadfence();
}

__global__ __launch_bounds__(512, 2) void gru_main(
    const float* __restrict__ x,
    const float* __restrict__ bz0, const float* __restrict__ bc0,
    const float* __restrict__ bz1, const float* __restrict__ bc1,
    const float* __restrict__ gamma, const float* __restrict__ beta,
    const unsigned short* __restrict__ wsw,
    unsigned short* __restrict__ gws,
    float* __restrict__ out) {
  __shared__ __align__(16) unsigned short lds[30720];  // 60 KB
  unsigned short* A0   = lds;           // [h0] 8 kt      (A for P2 kt0-7)
  unsigned short* A0r  = lds + 4096;    // [rh0] 8 kt     (A for P3)
  unsigned short* A1   = lds + 8192;    // [h1|h0] 16 kt  (A for P4)
  unsigned short* A1r  = lds + 16384;   // [rh1|h0] 16 kt (A for P5)
  unsigned short* xbuf = lds + 24576;   // 2 bufs x 2 kt
  float* pbuf = (float*)(lds + 26624);  // 256 x f32x4 partial exchange

  const int tid  = threadIdx.x;
  const int wave = tid >> 6;
  const int lane = tid & 63;
  const int l15  = lane & 15;
  const int quad = lane >> 4;
  const int g    = blockIdx.x & 15;     // group
  const int bq   = blockIdx.x >> 4;     // N-quarter 0..3
  const int p    = wave & 3;            // pair index
  const int isr  = wave >> 2;           // 0 = z-wave, 1 = r-wave
  const int ntg  = (bq << 2) | p;       // n-tile 0..15 of 256-col mats
  const int col  = (ntg << 4) | l15;    // owned col 0..255
  const int row0 = g << 4;

  for (int i = tid; i < 4096; i += 512) { A0[i] = 0; A1[i] = 0; }

  // owned C/D elem (m=quad*4+i, col) -> frag ushort index in an 8-tile buffer
  const int dlo = ((col >> 5) << 9) + ((((col >> 3) & 3) << 4) + (quad << 2)) * 8 + (col & 7);

  const float bg0  = bz0[isr * 256 + col];           // P2 gate bias (z or r)
  const float bg1  = bz1[isr * 256 + col];           // P4
  const float bc0v = isr ? 0.f : bc0[col];           // candidate bias on z-side
  const float bc1v = isr ? 0.f : bc1[col];

  // ---- pin 39 B tiles (156 VGPR) -- identical count on every wave ----
  const bf16x8* __restrict__ wsv = (const bf16x8*)wsw;
  bf16x8 pin[39];
  {
    const int tz0 = (isr ? (16 + ntg) : ntg) * 10;
    const int tc0 = 320 + ntg * 10 + (isr ? 5 : 0);
    const int tz1 = 480 + (isr ? (16 + ntg) : ntg) * 16;
    const int tc1 = 992 + ntg * 16 + (isr ? 8 : 0);
#pragma unroll
    for (int kt = 0; kt < 10; ++kt) pin[kt] = wsv[(tz0 + kt) * 64 + lane];
#pragma unroll
    for (int j = 0; j < 5; ++j) pin[10 + j] = wsv[(tc0 + j) * 64 + lane];
#pragma unroll
    for (int kt = 0; kt < 16; ++kt) pin[15 + kt] = wsv[(tz1 + kt) * 64 + lane];
#pragma unroll
    for (int j = 0; j < 8; ++j) pin[31 + j] = wsv[(tc1 + j) * 64 + lane];
#pragma unroll
    for (int i = 0; i < 39; ++i) asm volatile("" : "+v"(pin[i]));  // force residency
  }

  // gather buffers (ushort units) + counters
  unsigned short* grh0 = (unsigned short*)((char*)gws + GATHER_BASE + (size_t)g * GRP_STRIDE);
  unsigned short* gh0  = grh0 + 4096;
  unsigned short* grh1 = grh0 + 8192;
  unsigned short* gh1  = grh0 + 12288;
  int* ctr = (int*)((char*)gws + CTR_BASE) + g * 4 * CTR_PAD;

  // x staging: thread (row=tid>>5, c2=(tid&31)*2)
  const int xrow = tid >> 5;
  const int c2 = (tid & 31) << 1;
  const float* xpf = x + (size_t)(row0 + xrow) * (SEQL * IDIM) + c2;
  const int xdst = ((c2 >> 5) << 9) + (((((c2 >> 3) & 3) << 4) | xrow) << 3) + (c2 & 7);
  {
    float2 xv = *(const float2*)(xpf);
    xbuf[xdst] = f2bf(sanit(xv.x));
    xbuf[xdst + 1] = f2bf(sanit(xv.y));
  }

  f32x4 h0f = {0.f, 0.f, 0.f, 0.f};   // fp32 state, meaningful on z-waves
  f32x4 h1f = {0.f, 0.f, 0.f, 0.f};

  __syncthreads();

  for (int t = 0; t < SEQL; ++t) {
    const unsigned short* xb = xbuf + ((t & 1) << 10);
    const int tgt = 4 * (t + 1);
    const bool havex = (t + 1 < SEQL);
    float2 xn;
    if (havex) xn = *(const float2*)(xpf + (t + 1) * IDIM);

    // ---- P2: gate (z on z-waves, r on r-waves) over [h0|x] ----
    f32x4 acc = {bg0, bg0, bg0, bg0};
#pragma unroll
    for (int kt = 0; kt < 8; ++kt) {
      bf16x8 a = *(const bf16x8*)(A0 + (kt << 9) + (lane << 3));
      acc = __builtin_amdgcn_mfma_f32_16x16x32_bf16(a, pin[kt], acc, 0, 0, 0);
    }
#pragma unroll
    for (int kt = 8; kt < 10; ++kt) {
      bf16x8 a = *(const bf16x8*)(xb + ((kt - 8) << 9) + (lane << 3));
      acc = __builtin_amdgcn_mfma_f32_16x16x32_bf16(a, pin[kt], acc, 0, 0, 0);
    }
    float gv[4];
#pragma unroll
    for (int i = 0; i < 4; ++i) gv[i] = sigm(acc[i]);
    if (isr) {  // publish rh0 quarter
#pragma unroll
      for (int i = 0; i < 4; ++i)
        grh0[dlo + i * 8] = f2bf(gv[i] * bf2f(A0[dlo + i * 8]));
    }
    gsync(ctr + 0 * CTR_PAD, tgt, tid);
    *(uint4*)(A0r + tid * 8) = ((const uint4*)grh0)[tid];   // stage full rh0
    __syncthreads();

    // ---- P3: candidate0 partial (z: kt0-4, r: kt5-7 + x kt8-9) ----
    f32x4 pc = {bc0v, bc0v, bc0v, bc0v};
    if (!isr) {
#pragma unroll
      for (int j = 0; j < 5; ++j) {
        bf16x8 a = *(const bf16x8*)(A0r + (j << 9) + (lane << 3));
        pc = __builtin_amdgcn_mfma_f32_16x16x32_bf16(a, pin[10 + j], pc, 0, 0, 0);
      }
    } else {
#pragma unroll
      for (int j = 0; j < 3; ++j) {
        bf16x8 a = *(const bf16x8*)(A0r + ((5 + j) << 9) + (lane << 3));
        pc = __builtin_amdgcn_mfma_f32_16x16x32_bf16(a, pin[10 + j], pc, 0, 0, 0);
      }
#pragma unroll
      for (int j = 3; j < 5; ++j) {
        bf16x8 a = *(const bf16x8*)(xb + ((j - 3) << 9) + (lane << 3));
        pc = __builtin_amdgcn_mfma_f32_16x16x32_bf16(a, pin[10 + j], pc, 0, 0, 0);
      }
    }
    if (isr) *(f32x4*)(pbuf + (tid & 255) * 4) = pc;
    __syncthreads();
    if (!isr) {  // z-wave: h0 update (fp32), publish bf16 quarter
      f32x4 rp = *(const f32x4*)(pbuf + tid * 4);
#pragma unroll
      for (int i = 0; i < 4; ++i) {
        float ht = tanh_(pc[i] + rp[i]);
        h0f[i] = h0f[i] + gv[i] * (ht - h0f[i]);
        gh0[dlo + i * 8] = f2bf(h0f[i]);
      }
    }
    if (havex) {  // stage x[t+1] into the other buffer
      unsigned short* xb1 = xbuf + (((t + 1) & 1) << 10);
      xb1[xdst] = f2bf(sanit(xn.x));
      xb1[xdst + 1] = f2bf(sanit(xn.y));
    }
    gsync(ctr + 1 * CTR_PAD, tgt, tid);
    {
      uint4 d = ((const uint4*)gh0)[tid];
      *(uint4*)(A0 + tid * 8) = d;            // next step's P2
      *(uint4*)(A1 + 4096 + tid * 8) = d;     // P4 h0-part (k 256..511)
      *(uint4*)(A1r + 4096 + tid * 8) = d;    // P5 h0-part
    }
    __syncthreads();

    // ---- P4: layer1 gate over [h1|h0] ----
    f32x4 acc1 = {bg1, bg1, bg1, bg1};
#pragma unroll
    for (int kt = 0; kt < 16; ++kt) {
      bf16x8 a = *(const bf16x8*)(A1 + (kt << 9) + (lane << 3));
      acc1 = __builtin_amdgcn_mfma_f32_16x16x32_bf16(a, pin[15 + kt], acc1, 0, 0, 0);
    }
    float gv1[4];
#pragma unroll
    for (int i = 0; i < 4; ++i) gv1[i] = sigm(acc1[i]);
    if (isr) {
#pragma unroll
      for (int i = 0; i < 4; ++i)
        grh1[dlo + i * 8] = f2bf(gv1[i] * bf2f(A1[dlo + i * 8]));
    }
    gsync(ctr + 2 * CTR_PAD, tgt, tid);
    *(uint4*)(A1r + tid * 8) = ((const uint4*)grh1)[tid];   // rh1 -> kt0-7
    __syncthreads();

    // ---- P5: candidate1 partial (z: kt0-7 rh1-part, r: kt8-15 h0-part) ----
    f32x4 pc1 = {bc1v, bc1v, bc1v, bc1v};
    {
      const int kb = isr ? 8 : 0;
#pragma unroll
      for (int j = 0; j < 8; ++j) {
        bf16x8 a = *(const bf16x8*)(A1r + ((kb + j) << 9) + (lane << 3));
        pc1 = __builtin_amdgcn_mfma_f32_16x16x32_bf16(a, pin[31 + j], pc1, 0, 0, 0);
      }
    }
    if (isr) *(f32x4*)(pbuf + (tid & 255) * 4) = pc1;
    __syncthreads();
    if (!isr) {
      f32x4 rp = *(const f32x4*)(pbuf + tid * 4);
#pragma unroll
      for (int i = 0; i < 4; ++i) {
        float ht = tanh_(pc1[i] + rp[i]);
        h1f[i] = h1f[i] + gv1[i] * (ht - h1f[i]);
        gh1[dlo + i * 8] = f2bf(h1f[i]);
      }
    }
    gsync(ctr + 3 * CTR_PAD, tgt, tid);
    *(uint4*)(A1 + tid * 8) = ((const uint4*)gh1)[tid];     // h1 -> kt0-7
    __syncthreads();
  }

  // ---- Epilogue: LayerNorm over full h1 (bf16, staged in A1 kt0-7) ----
  const int r = tid >> 5;        // row 0..15
  const int i5 = tid & 31;
  float v[8], s = 0.f, sq = 0.f;
#pragma unroll
  for (int j = 0; j < 8; ++j) {
    int c = i5 + (j << 5);
    int idx = ((c >> 5) << 9) + (((((c >> 3) & 3) << 4) | r) << 3) + (c & 7);
    v[j] = bf2f(A1[idx]);
    s += v[j];
    sq += v[j] * v[j];
  }
#pragma unroll
  for (int off = 16; off > 0; off >>= 1) {
    s  += __shfl_xor(s, off);
    sq += __shfl_xor(sq, off);
  }
  float mean = s * (1.f / 256.f);
  float var  = sq * (1.f / 256.f) - mean * mean;
  float rstd = rsqrtf(var + 1e-5f);
  float* op = out + (size_t)(row0 + r) * 256;
  {
    int c0 = (bq << 6) + i5;        // this block writes its own quarter cols
    int c1 = c0 + 32;
    op[c0] = (v[2 * bq] - mean) * rstd * gamma[c0] + beta[c0];
    op[c1] = (v[2 * bq + 1] - mean) * rstd * gamma[c1] + beta[c1];
  }
}

extern "C" void kernel_launch(void* const* d_in, const int* in_sizes, int n_in,
                              void* d_out, int out_size, void* d_ws, size_t ws_size,
                              hipStream_t stream) {
  const float* x     = (const float*)d_in[0];
  const float* Wz0   = (const float*)d_in[1];
  const float* bz0   = (const float*)d_in[2];
  const float* Wc0   = (const float*)d_in[3];
  const float* bc0   = (const float*)d_in[4];
  const float* Wz1   = (const float*)d_in[5];
  const float* bz1   = (const float*)d_in[6];
  const float* Wc1   = (const float*)d_in[7];
  const float* bc1   = (const float*)d_in[8];
  const float* gamma = (const float*)d_in[9];
  const float* beta  = (const float*)d_in[10];
  unsigned short* ws = (unsigned short*)d_ws;
  float* out = (float*)d_out;

  hipMemsetAsync((char*)d_ws + CTR_BASE, 0, 16 * 4 * CTR_PAD * sizeof(int), stream);
  hipLaunchKernelGGL(prep_weights, dim3(2496), dim3(256), 0, stream, Wz0, Wc0, Wz1, Wc1, ws);
  hipLaunchKernelGGL(gru_main, dim3(64), dim3(512), 0, stream,
                     x, bz0, bc0, bz1, bc1, gamma, beta, ws, ws, out);
}

// Round 7
// 3670.522 us; speedup vs baseline: 9.6581x; 9.6581x over previous
//
#include <hip/hip_runtime.h>

// TimeframeEncoder R7: 3-stage chunked pipeline, weights CU-resident.
// = R5 structure (register-pinned weights in ALL stages) + R5's frame-copy
// bug fixed (full 4096-ushort frames) + fp32 LayerNorm. R6's undersized
// LDS weight staging (32 tiles staged, 128 indexed -> OOB) is reverted.
// 16 groups x 3 blocks (256 thr = 4 waves, __launch_bounds__(256,1) -> 512
// VGPR/wave). Group g owns batch rows [16g,16g+16).
//  Stage A: layer0; pins Wz0 z/r + Wc0 h-parts (96 tiles = 384 VGPR); x-part LDS.
//  Stage B: layer1 h0-contribution GEMM; pins Wz1 z/r + Wc1 h0-halves (384 VGPR),
//           no frame prefetch (keeps peak regs < 512).
//  Stage C: layer1 recurrence; pins Wz1 z/r + Wc1 h1-halves; fp32 LN output.
// A->B->C via global rings in d_ws, CH=8-step chunks, depth 2, 1 fence/chunk.

#define SEQL 512
#define CH 8
#define NCH 64

#define RB0  1310720u                   // rings base (weights end 1,277,952)
#define GSTR 524288u                    // per group: h0 ring 128KB + partials 384KB
#define CTRB (RB0 + 16u * GSTR)         // counters: 16 groups x 64 B

typedef __bf16 bf16x8 __attribute__((ext_vector_type(8)));
typedef float f32x4 __attribute__((ext_vector_type(4)));

__device__ __forceinline__ unsigned short f2bf(float f) {
  unsigned int u = __builtin_bit_cast(unsigned int, f);
  u += 0x7fffu + ((u >> 16) & 1u);
  return (unsigned short)(u >> 16);
}
__device__ __forceinline__ float bf2f(unsigned short u) {
  unsigned int v = ((unsigned int)u) << 16;
  return __builtin_bit_cast(float, v);
}
__device__ __forceinline__ float sigm(float x) { return 1.0f / (1.0f + __expf(-x)); }
__device__ __forceinline__ float tanh_(float x) { return 1.0f - 2.0f / (__expf(2.0f * x) + 1.0f); }
__device__ __forceinline__ float sanit(float v) {
  if (!(v == v)) return 0.f;
  if (isinf(v)) return v > 0.f ? 10.f : -10.f;
  return v;
}

// Weight prep (layout verified R1-R4): bf16 B-fragments, tile = 512 ushort,
// lane L holds B[k=(L>>4)*8+j][n=L&15]. Wz0p tiles [0,320) (nt<32,kt<10);
// Wc0p base 320 (nt<16,kt<10); Wz1p base 480 (nt<32,kt<16); Wc1p base 992.
__global__ __launch_bounds__(256) void prep_weights(
    const float* __restrict__ Wz0, const float* __restrict__ Wc0,
    const float* __restrict__ Wz1, const float* __restrict__ Wc1,
    unsigned short* __restrict__ ws) {
  int idx = blockIdx.x * 256 + threadIdx.x;  // 638976 threads
  const float* W;
  int stride, KT, base;
  if (idx < 163840)      { W = Wz0; stride = 768; KT = 10; base = 0; }
  else if (idx < 245760) { W = Wc0; stride = 256; KT = 10; base = 163840; idx -= 163840; }
  else if (idx < 507904) { W = Wz1; stride = 768; KT = 16; base = 245760; idx -= 245760; }
  else                   { W = Wc1; stride = 256; KT = 16; base = 507904; idx -= 507904; }
  int tile = idx >> 9;
  int t = idx & 511;
  int nt = tile / KT;
  int kt = tile - nt * KT;
  int n15 = t & 15;
  int klocal = t >> 4;
  int k = (kt << 5) + klocal;
  int n = (nt << 4) + n15;
  int lane = ((klocal >> 3) << 4) | n15;
  int j = klocal & 7;
  ws[base + (tile << 9) + (lane << 3) + j] = f2bf(W[k * stride + n]);
}

__device__ __forceinline__ void waitge(int* p, int v, int tid) {
  __syncthreads();
  if (tid == 0) {
    long it = 0;
    while (__hip_atomic_load(p, __ATOMIC_ACQUIRE, __HIP_MEMORY_SCOPE_AGENT) < v) {
      __builtin_amdgcn_s_sleep(2);
      if (++it > (1L << 26)) break;  // valve against true deadlock
    }
  }
  __syncthreads();
  __threadfence();
}
__device__ __forceinline__ void publish(int* p, int v, int tid) {
  __threadfence();
  __syncthreads();
  if (tid == 0) __hip_atomic_store(p, v, __ATOMIC_RELEASE, __HIP_MEMORY_SCOPE_AGENT);
}

#define DLOC(c) ((((c) >> 5) << 9) + (((((c) >> 3) & 3) << 4) + (quad << 2)) * 8 + ((c) & 7))
#define MFMA(a, b, c) __builtin_amdgcn_mfma_f32_16x16x32_bf16((a), (b), (c), 0, 0, 0)

__global__ __launch_bounds__(256, 1) void gru_pipe(
    const float* __restrict__ x,
    const float* __restrict__ bz0, const float* __restrict__ bc0,
    const float* __restrict__ bz1, const float* __restrict__ bc1,
    const float* __restrict__ gamma, const float* __restrict__ beta,
    const unsigned short* __restrict__ wsw,
    unsigned short* __restrict__ gws,
    float* __restrict__ out) {
  __shared__ __align__(16) unsigned short lds[59392];  // 116 KB (stage A max)
  const int tid  = threadIdx.x;
  const int wave = tid >> 6;   // 0..3
  const int lane = tid & 63;
  const int l15  = lane & 15;
  const int quad = lane >> 4;
  const int stage = blockIdx.x >> 4;
  const int g     = blockIdx.x & 15;
  const int row0  = g << 4;

  const bf16x8* __restrict__ wsv = (const bf16x8*)wsw;
  unsigned short* ringh = gws + (RB0 >> 1) + (size_t)g * (GSTR >> 1);  // h0 frames
  unsigned short* ringp = ringh + 65536;                               // partials
  int* ctr = (int*)((char*)gws + CTRB) + g * 16;  // [0]A_pub [1]B_pub [2]B_ack [3]C_ack

  if (stage == 0) {
    // ================= Stage A: layer0 =================
    unsigned short* h0f  = lds;            // 8 kt A-frag of h0
    unsigned short* rh0f = lds + 4096;
    unsigned short* xf   = lds + 8192;     // 2 bufs x 2 kt
    unsigned short* xw   = lds + 10240;    // x-part B tiles: 96 x 512 ushort
    for (int u = tid; u < 6144; u += 256) {   // stage x-part weights to LDS
      int flat = u << 3, ti = flat >> 9, q = flat & 511, srct;
      if (ti < 64) srct = (ti >> 1) * 10 + 8 + (ti & 1);
      else         srct = 320 + ((ti - 64) >> 1) * 10 + 8 + (ti & 1);
      *(uint4*)(xw + flat) = *(const uint4*)(wsw + srct * 512 + q);
    }
    for (int i = tid; i < 4096; i += 256) h0f[i] = 0;

    bf16x8 pz[4][8], pr[4][8], pc[4][8];   // 96 tiles = 384 VGPR/lane
#pragma unroll
    for (int j = 0; j < 4; ++j) {
      const int zt = 4 * wave + j;
#pragma unroll
      for (int k = 0; k < 8; ++k) {
        pz[j][k] = wsv[(zt * 10 + k) * 64 + lane];
        pr[j][k] = wsv[((16 + zt) * 10 + k) * 64 + lane];
        pc[j][k] = wsv[(320 + zt * 10 + k) * 64 + lane];
      }
    }
#pragma unroll
    for (int j = 0; j < 4; ++j)
#pragma unroll
      for (int k = 0; k < 8; ++k)
        asm volatile("" : "+v"(pz[j][k]), "+v"(pr[j][k]), "+v"(pc[j][k]));

    float bzz[4], bzr[4], bcc[4];
    int dloc[4];
#pragma unroll
    for (int j = 0; j < 4; ++j) {
      const int col = 64 * wave + 16 * j + l15;
      bzz[j] = bz0[col]; bzr[j] = bz0[256 + col]; bcc[j] = bc0[col];
      dloc[j] = DLOC(col);
    }
    f32x4 h0s[4] = {{0,0,0,0},{0,0,0,0},{0,0,0,0},{0,0,0,0}};

    const int xrow = tid >> 4, c4 = (tid & 15) << 2;
    const float* xp = x + (size_t)(row0 + xrow) * (SEQL * 64) + c4;
    const int xbase = ((c4 >> 5) << 9) + ((((c4 >> 3) & 3) << 4) + xrow) * 8 + (c4 & 7);
    {
      float4 xv = *(const float4*)xp;
      xf[xbase] = f2bf(sanit(xv.x)); xf[xbase + 1] = f2bf(sanit(xv.y));
      xf[xbase + 2] = f2bf(sanit(xv.z)); xf[xbase + 3] = f2bf(sanit(xv.w));
    }
    __syncthreads();

    for (int ch = 0; ch < NCH; ++ch) {
      if (ch >= 2) waitge(ctr + 2, ch - 1, tid);   // B done with this slot
      unsigned short* slot = ringh + (ch & 1) * (CH * 4096);
      for (int s = 0; s < CH; ++s) {
        const int t = (ch << 3) + s;
        if (s > 0) {  // FULL 4096-ushort frame copy (the R5 bug, fixed)
          unsigned short* dst = slot + (s - 1) * 4096;
          *(uint4*)(dst + tid * 8)        = *(const uint4*)(h0f + tid * 8);
          *(uint4*)(dst + 2048 + tid * 8) = *(const uint4*)(h0f + 2048 + tid * 8);
        }
        const unsigned short* xb = xf + ((t & 1) << 10);
        const bool havex = (t + 1 < SEQL);
        float4 xn;
        if (havex) xn = *(const float4*)(xp + (t + 1) * 64);

        f32x4 za[4], ra[4];
#pragma unroll
        for (int j = 0; j < 4; ++j) { za[j] = {bzz[j],bzz[j],bzz[j],bzz[j]}; ra[j] = {bzr[j],bzr[j],bzr[j],bzr[j]}; }
#pragma unroll
        for (int k = 0; k < 8; ++k) {
          bf16x8 a = *(const bf16x8*)(h0f + (k << 9) + (lane << 3));
#pragma unroll
          for (int j = 0; j < 4; ++j) { za[j] = MFMA(a, pz[j][k], za[j]); ra[j] = MFMA(a, pr[j][k], ra[j]); }
        }
#pragma unroll
        for (int k = 0; k < 2; ++k) {
          bf16x8 a = *(const bf16x8*)(xb + (k << 9) + (lane << 3));
#pragma unroll
          for (int j = 0; j < 4; ++j) {
            bf16x8 bz_ = *(const bf16x8*)(xw + ((((4 * wave + j) << 1) | k) << 9) + (lane << 3));
            bf16x8 br_ = *(const bf16x8*)(xw + ((((16 + 4 * wave + j) << 1) | k) << 9) + (lane << 3));
            za[j] = MFMA(a, bz_, za[j]); ra[j] = MFMA(a, br_, ra[j]);
          }
        }
        float zg[4][4];
#pragma unroll
        for (int j = 0; j < 4; ++j)
#pragma unroll
          for (int i = 0; i < 4; ++i) {
            zg[j][i] = sigm(za[j][i]);
            rh0f[dloc[j] + i * 8] = f2bf(sigm(ra[j][i]) * h0s[j][i]);
          }
        __syncthreads();

        f32x4 ca[4];
#pragma unroll
        for (int j = 0; j < 4; ++j) ca[j] = {bcc[j],bcc[j],bcc[j],bcc[j]};
#pragma unroll
        for (int k = 0; k < 8; ++k) {
          bf16x8 a = *(const bf16x8*)(rh0f + (k << 9) + (lane << 3));
#pragma unroll
          for (int j = 0; j < 4; ++j) ca[j] = MFMA(a, pc[j][k], ca[j]);
        }
#pragma unroll
        for (int k = 0; k < 2; ++k) {
          bf16x8 a = *(const bf16x8*)(xb + (k << 9) + (lane << 3));
#pragma unroll
          for (int j = 0; j < 4; ++j) {
            bf16x8 bc_ = *(const bf16x8*)(xw + 32768 + ((((4 * wave + j) << 1) | k) << 9) + (lane << 3));
            ca[j] = MFMA(a, bc_, ca[j]);
          }
        }
#pragma unroll
        for (int j = 0; j < 4; ++j)
#pragma unroll
          for (int i = 0; i < 4; ++i) {
            float ht = tanh_(ca[j][i]);
            float hn = h0s[j][i] + zg[j][i] * (ht - h0s[j][i]);
            h0s[j][i] = hn;
            h0f[dloc[j] + i * 8] = f2bf(hn);
          }
        if (havex) {
          unsigned short* xb1 = xf + (((t + 1) & 1) << 10);
          xb1[xbase] = f2bf(sanit(xn.x)); xb1[xbase + 1] = f2bf(sanit(xn.y));
          xb1[xbase + 2] = f2bf(sanit(xn.z)); xb1[xbase + 3] = f2bf(sanit(xn.w));
        }
        __syncthreads();
      }
      {  // final frame of the chunk (full frame)
        unsigned short* dst = slot + 7 * 4096;
        *(uint4*)(dst + tid * 8)        = *(const uint4*)(h0f + tid * 8);
        *(uint4*)(dst + 2048 + tid * 8) = *(const uint4*)(h0f + 2048 + tid * 8);
      }
      publish(ctr + 0, ch + 1, tid);
    }
  } else if (stage == 1) {
    // ============ Stage B: layer1 h0-contribution (pure GEMM) ============
    bf16x8 p1[4][8], p2[4][8], p3[4][8];  // Wz1-z, Wz1-r, Wc1 h0-halves (kt 8..15)
#pragma unroll
    for (int j = 0; j < 4; ++j) {
      const int nt = 4 * wave + j;
#pragma unroll
      for (int k = 0; k < 8; ++k) {
        p1[j][k] = wsv[(480 + nt * 16 + 8 + k) * 64 + lane];
        p2[j][k] = wsv[(480 + (16 + nt) * 16 + 8 + k) * 64 + lane];
        p3[j][k] = wsv[(992 + nt * 16 + 8 + k) * 64 + lane];
      }
    }
#pragma unroll
    for (int j = 0; j < 4; ++j)
#pragma unroll
      for (int k = 0; k < 8; ++k)
        asm volatile("" : "+v"(p1[j][k]), "+v"(p2[j][k]), "+v"(p3[j][k]));
    float b1[4], b2[4], b3[4];
#pragma unroll
    for (int j = 0; j < 4; ++j) {
      const int col = 64 * wave + 16 * j + l15;
      b1[j] = bz1[col]; b2[j] = bz1[256 + col]; b3[j] = bc1[col];
    }
    for (int ch = 0; ch < NCH; ++ch) {
      waitge(ctr + 0, ch + 1, tid);                 // A published chunk
      if (ch >= 2) waitge(ctr + 3, ch - 1, tid);    // C done with this slot
      const unsigned short* hslot = ringh + (ch & 1) * (CH * 4096);
      unsigned short* pslot = ringp + (ch & 1) * (CH * 12288);
      for (int s = 0; s < CH; ++s) {
        uint4 cf[8];   // single-buffered frame read (keeps regs < 512)
#pragma unroll
        for (int k = 0; k < 8; ++k)
          cf[k] = *(const uint4*)(hslot + s * 4096 + (k << 9) + (lane << 3));
        f32x4 za[4] = {{0,0,0,0},{0,0,0,0},{0,0,0,0},{0,0,0,0}};
        f32x4 ra[4] = {{0,0,0,0},{0,0,0,0},{0,0,0,0},{0,0,0,0}};
        f32x4 ca[4] = {{0,0,0,0},{0,0,0,0},{0,0,0,0},{0,0,0,0}};
#pragma unroll
        for (int k = 0; k < 8; ++k) {
          bf16x8 a = __builtin_bit_cast(bf16x8, cf[k]);
#pragma unroll
          for (int j = 0; j < 4; ++j) {
            za[j] = MFMA(a, p1[j][k], za[j]);
            ra[j] = MFMA(a, p2[j][k], ra[j]);
            ca[j] = MFMA(a, p3[j][k], ca[j]);
          }
        }
        unsigned short* pf = pslot + s * 12288;
#pragma unroll
        for (int j = 0; j < 4; ++j) {
          ushort4 vz, vr, vc;
          vz.x = f2bf(za[j][0] + b1[j]); vz.y = f2bf(za[j][1] + b1[j]);
          vz.z = f2bf(za[j][2] + b1[j]); vz.w = f2bf(za[j][3] + b1[j]);
          vr.x = f2bf(ra[j][0] + b2[j]); vr.y = f2bf(ra[j][1] + b2[j]);
          vr.z = f2bf(ra[j][2] + b2[j]); vr.w = f2bf(ra[j][3] + b2[j]);
          vc.x = f2bf(ca[j][0] + b3[j]); vc.y = f2bf(ca[j][1] + b3[j]);
          vc.z = f2bf(ca[j][2] + b3[j]); vc.w = f2bf(ca[j][3] + b3[j]);
          *(ushort4*)(pf + (4 * wave + j) * 256 + lane * 4) = vz;
          *(ushort4*)(pf + (16 + 4 * wave + j) * 256 + lane * 4) = vr;
          *(ushort4*)(pf + (32 + 4 * wave + j) * 256 + lane * 4) = vc;
        }
      }
      publish(ctr + 1, ch + 1, tid);
      if (tid == 0)
        __hip_atomic_store(ctr + 2, ch + 1, __ATOMIC_RELEASE, __HIP_MEMORY_SCOPE_AGENT);
    }
  } else {
    // ============ Stage C: layer1 recurrence + LN output ============
    unsigned short* h1f  = lds;
    unsigned short* rh1f = lds + 4096;
    bf16x8 q1[4][8], q2[4][8], q3[4][8];  // h1-halves (kt 0..7)
#pragma unroll
    for (int j = 0; j < 4; ++j) {
      const int nt = 4 * wave + j;
#pragma unroll
      for (int k = 0; k < 8; ++k) {
        q1[j][k] = wsv[(480 + nt * 16 + k) * 64 + lane];
        q2[j][k] = wsv[(480 + (16 + nt) * 16 + k) * 64 + lane];
        q3[j][k] = wsv[(992 + nt * 16 + k) * 64 + lane];
      }
    }
#pragma unroll
    for (int j = 0; j < 4; ++j)
#pragma unroll
      for (int k = 0; k < 8; ++k)
        asm volatile("" : "+v"(q1[j][k]), "+v"(q2[j][k]), "+v"(q3[j][k]));
    for (int i = tid; i < 4096; i += 256) h1f[i] = 0;
    int dloc[4];
#pragma unroll
    for (int j = 0; j < 4; ++j) dloc[j] = DLOC(64 * wave + 16 * j + l15);
    f32x4 h1s[4] = {{0,0,0,0},{0,0,0,0},{0,0,0,0},{0,0,0,0}};
    __syncthreads();

    for (int ch = 0; ch < NCH; ++ch) {
      waitge(ctr + 1, ch + 1, tid);
      const unsigned short* pslot = ringp + (ch & 1) * (CH * 12288);
      for (int s = 0; s < CH; ++s) {
        const unsigned short* pf = pslot + s * 12288;
        ushort4 pz4[4], pr4[4], pc4[4];
#pragma unroll
        for (int j = 0; j < 4; ++j) {
          pz4[j] = *(const ushort4*)(pf + (4 * wave + j) * 256 + lane * 4);
          pr4[j] = *(const ushort4*)(pf + (16 + 4 * wave + j) * 256 + lane * 4);
          pc4[j] = *(const ushort4*)(pf + (32 + 4 * wave + j) * 256 + lane * 4);
        }
        f32x4 za[4] = {{0,0,0,0},{0,0,0,0},{0,0,0,0},{0,0,0,0}};
        f32x4 ra[4] = {{0,0,0,0},{0,0,0,0},{0,0,0,0},{0,0,0,0}};
#pragma unroll
        for (int k = 0; k < 8; ++k) {
          bf16x8 a = *(const bf16x8*)(h1f + (k << 9) + (lane << 3));
#pragma unroll
          for (int j = 0; j < 4; ++j) { za[j] = MFMA(a, q1[j][k], za[j]); ra[j] = MFMA(a, q2[j][k], ra[j]); }
        }
        float zg[4][4];
        const unsigned short* pzs = (const unsigned short*)pz4;
        const unsigned short* prs = (const unsigned short*)pr4;
#pragma unroll
        for (int j = 0; j < 4; ++j)
#pragma unroll
          for (int i = 0; i < 4; ++i) {
            zg[j][i] = sigm(za[j][i] + bf2f(pzs[j * 4 + i]));
            float r = sigm(ra[j][i] + bf2f(prs[j * 4 + i]));
            rh1f[dloc[j] + i * 8] = f2bf(r * h1s[j][i]);
          }
        __syncthreads();

        f32x4 ca[4] = {{0,0,0,0},{0,0,0,0},{0,0,0,0},{0,0,0,0}};
#pragma unroll
        for (int k = 0; k < 8; ++k) {
          bf16x8 a = *(const bf16x8*)(rh1f + (k << 9) + (lane << 3));
#pragma unroll
          for (int j = 0; j < 4; ++j) ca[j] = MFMA(a, q3[j][k], ca[j]);
        }
        const unsigned short* pcs = (const unsigned short*)pc4;
#pragma unroll
        for (int j = 0; j < 4; ++j)
#pragma unroll
          for (int i = 0; i < 4; ++i) {
            float ht = tanh_(ca[j][i] + bf2f(pcs[j * 4 + i]));
            float hn = h1s[j][i] + zg[j][i] * (ht - h1s[j][i]);
            h1s[j][i] = hn;
            h1f[dloc[j] + i * 8] = f2bf(hn);
          }
        __syncthreads();
      }
      publish(ctr + 3, ch + 1, tid);
    }

    // LayerNorm from fp32 h1 state via LDS staging (h1f/rh1f regions dead)
    float* h1buf = (float*)lds;   // 16 x 256 fp32 = 16 KB
#pragma unroll
    for (int j = 0; j < 4; ++j)
#pragma unroll
      for (int i = 0; i < 4; ++i)
        h1buf[(quad * 4 + i) * 256 + 64 * wave + 16 * j + l15] = h1s[j][i];
    __syncthreads();

    const int r = tid >> 4, cl = tid & 15;
    float v[16], s = 0.f, sq = 0.f;
#pragma unroll
    for (int jj = 0; jj < 16; ++jj) {
      v[jj] = h1buf[r * 256 + cl + (jj << 4)];
      s += v[jj]; sq += v[jj] * v[jj];
    }
#pragma unroll
    for (int off = 8; off > 0; off >>= 1) {   // 16-lane group reduce
      s  += __shfl_xor(s, off);
      sq += __shfl_xor(sq, off);
    }
    const float mean = s * (1.f / 256.f);
    const float var  = sq * (1.f / 256.f) - mean * mean;
    const float rstd = rsqrtf(var + 1e-5f);
    float* op = out + (size_t)(row0 + r) * 256;
#pragma unroll
    for (int jj = 0; jj < 16; ++jj) {
      const int c = cl + (jj << 4);
      op[c] = (v[jj] - mean) * rstd * gamma[c] + beta[c];
    }
  }
}

extern "C" void kernel_launch(void* const* d_in, const int* in_sizes, int n_in,
                              void* d_out, int out_size, void* d_ws, size_t ws_size,
                              hipStream_t stream) {
  const float* x     = (const float*)d_in[0];
  const float* Wz0   = (const float*)d_in[1];
  const float* bz0   = (const float*)d_in[2];
  const float* Wc0   = (const float*)d_in[3];
  const float* bc0   = (const float*)d_in[4];
  const float* Wz1   = (const float*)d_in[5];
  const float* bz1   = (const float*)d_in[6];
  const float* Wc1   = (const float*)d_in[7];
  const float* bc1   = (const float*)d_in[8];
  const float* gamma = (const float*)d_in[9];
  const float* beta  = (const float*)d_in[10];
  unsigned short* ws = (unsigned short*)d_ws;
  float* out = (float*)d_out;

  hipMemsetAsync((char*)d_ws + CTRB, 0, 16 * 64, stream);
  hipLaunchKernelGGL(prep_weights, dim3(2496), dim3(256), 0, stream, Wz0, Wc0, Wz1, Wc1, ws);
  hipLaunchKernelGGL(gru_pipe, dim3(48), dim3(256), 0, stream,
                     x, bz0, bc0, bz1, bc1, gamma, beta, ws, ws, out);
}

// Round 8
// 3151.019 us; speedup vs baseline: 11.2504x; 1.1649x over previous
//
#include <hip/hip_runtime.h>

// TimeframeEncoder R8: R7's 3-stage chunked pipeline (weights CU-resident,
// register-pinned) with the device-scope FENCES REMOVED. R7's __threadfence
// (full L2 wbl2+inv per chunk, 48 blocks x 64 chunks sharing per-XCD L2) was
// ~70% of runtime. Ring data now moves via relaxed agent-scope atomics
// (sc0 sc1 write-through stores / cache-bypass loads); ordering by per-thread
// s_waitcnt vmcnt(0) + block barrier + relaxed counter store. No wbl2/inv.
// 16 groups x 3 blocks (256 thr): A=layer0, B=layer1 h0-GEMM, C=layer1 rec+LN.

#define SEQL 512
#define CH 8
#define NCH 64

#define RB0  1310720u                   // rings base (weights end 1,277,952)
#define GSTR 524288u                    // per group: h0 ring 128KB + partials 384KB
#define CTRB (RB0 + 16u * GSTR)         // counters: 16 groups x 64 B

typedef __bf16 bf16x8 __attribute__((ext_vector_type(8)));
typedef float f32x4 __attribute__((ext_vector_type(4)));
typedef unsigned long long u64;

__device__ __forceinline__ unsigned short f2bf(float f) {
  unsigned int u = __builtin_bit_cast(unsigned int, f);
  u += 0x7fffu + ((u >> 16) & 1u);
  return (unsigned short)(u >> 16);
}
__device__ __forceinline__ float bf2f(unsigned short u) {
  unsigned int v = ((unsigned int)u) << 16;
  return __builtin_bit_cast(float, v);
}
__device__ __forceinline__ float sigm(float x) { return 1.0f / (1.0f + __expf(-x)); }
__device__ __forceinline__ float tanh_(float x) { return 1.0f - 2.0f / (__expf(2.0f * x) + 1.0f); }
__device__ __forceinline__ float sanit(float v) {
  if (!(v == v)) return 0.f;
  if (isinf(v)) return v > 0.f ? 10.f : -10.f;
  return v;
}

// agent-coherent 8B data access (global_store/load_dwordx2 sc0 sc1):
// write-through to device coherence point / read bypassing stale L1/L2.
__device__ __forceinline__ void st8(u64* p, u64 v) {
  __hip_atomic_store(p, v, __ATOMIC_RELAXED, __HIP_MEMORY_SCOPE_AGENT);
}
__device__ __forceinline__ u64 ld8(const u64* p) {
  return __hip_atomic_load(p, __ATOMIC_RELAXED, __HIP_MEMORY_SCOPE_AGENT);
}

// Weight prep (layout verified R1-R7): bf16 B-fragments, tile = 512 ushort,
// lane L holds B[k=(L>>4)*8+j][n=L&15]. Wz0p tiles [0,320) (nt<32,kt<10);
// Wc0p base 320 (nt<16,kt<10); Wz1p base 480 (nt<32,kt<16); Wc1p base 992.
__global__ __launch_bounds__(256) void prep_weights(
    const float* __restrict__ Wz0, const float* __restrict__ Wc0,
    const float* __restrict__ Wz1, const float* __restrict__ Wc1,
    unsigned short* __restrict__ ws) {
  int idx = blockIdx.x * 256 + threadIdx.x;  // 638976 threads
  const float* W;
  int stride, KT, base;
  if (idx < 163840)      { W = Wz0; stride = 768; KT = 10; base = 0; }
  else if (idx < 245760) { W = Wc0; stride = 256; KT = 10; base = 163840; idx -= 163840; }
  else if (idx < 507904) { W = Wz1; stride = 768; KT = 16; base = 245760; idx -= 245760; }
  else                   { W = Wc1; stride = 256; KT = 16; base = 507904; idx -= 507904; }
  int tile = idx >> 9;
  int t = idx & 511;
  int nt = tile / KT;
  int kt = tile - nt * KT;
  int n15 = t & 15;
  int klocal = t >> 4;
  int k = (kt << 5) + klocal;
  int n = (nt << 4) + n15;
  int lane = ((klocal >> 3) << 4) | n15;
  int j = klocal & 7;
  ws[base + (tile << 9) + (lane << 3) + j] = f2bf(W[k * stride + n]);
}

__device__ __forceinline__ void waitge(int* p, int v, int tid) {
  __syncthreads();
  if (tid == 0) {
    long it = 0;
    while (__hip_atomic_load(p, __ATOMIC_RELAXED, __HIP_MEMORY_SCOPE_AGENT) < v) {
      __builtin_amdgcn_s_sleep(2);
      if (++it > (1L << 26)) break;  // valve against true deadlock
    }
  }
  __syncthreads();
}
// all data st8s retired (per-thread vmcnt) -> barrier -> counter store
__device__ __forceinline__ void publish(int* p, int v, int tid) {
  asm volatile("s_waitcnt vmcnt(0)" ::: "memory");
  __syncthreads();
  if (tid == 0) __hip_atomic_store(p, v, __ATOMIC_RELAXED, __HIP_MEMORY_SCOPE_AGENT);
}

#define DLOC(c) ((((c) >> 5) << 9) + (((((c) >> 3) & 3) << 4) + (quad << 2)) * 8 + ((c) & 7))
#define MFMA(a, b, c) __builtin_amdgcn_mfma_f32_16x16x32_bf16((a), (b), (c), 0, 0, 0)

union UB { u64 q[2]; bf16x8 v; };

__global__ __launch_bounds__(256, 1) void gru_pipe(
    const float* __restrict__ x,
    const float* __restrict__ bz0, const float* __restrict__ bc0,
    const float* __restrict__ bz1, const float* __restrict__ bc1,
    const float* __restrict__ gamma, const float* __restrict__ beta,
    const unsigned short* __restrict__ wsw,
    unsigned short* __restrict__ gws,
    float* __restrict__ out) {
  __shared__ __align__(16) unsigned short lds[59392];  // 116 KB (stage A max)
  const int tid  = threadIdx.x;
  const int wave = tid >> 6;   // 0..3
  const int lane = tid & 63;
  const int l15  = lane & 15;
  const int quad = lane >> 4;
  const int stage = blockIdx.x >> 4;
  const int g     = blockIdx.x & 15;
  const int row0  = g << 4;

  const bf16x8* __restrict__ wsv = (const bf16x8*)wsw;
  unsigned short* ringh = gws + (RB0 >> 1) + (size_t)g * (GSTR >> 1);  // h0 frames
  unsigned short* ringp = ringh + 65536;                               // partials
  int* ctr = (int*)((char*)gws + CTRB) + g * 16;  // [0]A_pub [1]B_pub [2]B_ack [3]C_ack

  if (stage == 0) {
    // ================= Stage A: layer0 =================
    unsigned short* h0f  = lds;            // 8 kt A-frag of h0
    unsigned short* rh0f = lds + 4096;
    unsigned short* xf   = lds + 8192;     // 2 bufs x 2 kt
    unsigned short* xw   = lds + 10240;    // x-part B tiles: 96 x 512 ushort
    for (int u = tid; u < 6144; u += 256) {   // stage x-part weights to LDS
      int flat = u << 3, ti = flat >> 9, q = flat & 511, srct;
      if (ti < 64) srct = (ti >> 1) * 10 + 8 + (ti & 1);
      else         srct = 320 + ((ti - 64) >> 1) * 10 + 8 + (ti & 1);
      *(uint4*)(xw + flat) = *(const uint4*)(wsw + srct * 512 + q);
    }
    for (int i = tid; i < 4096; i += 256) h0f[i] = 0;

    bf16x8 pz[4][8], pr[4][8], pc[4][8];   // 96 tiles pinned (VGPR+AGPR)
#pragma unroll
    for (int j = 0; j < 4; ++j) {
      const int zt = 4 * wave + j;
#pragma unroll
      for (int k = 0; k < 8; ++k) {
        pz[j][k] = wsv[(zt * 10 + k) * 64 + lane];
        pr[j][k] = wsv[((16 + zt) * 10 + k) * 64 + lane];
        pc[j][k] = wsv[(320 + zt * 10 + k) * 64 + lane];
      }
    }
#pragma unroll
    for (int j = 0; j < 4; ++j)
#pragma unroll
      for (int k = 0; k < 8; ++k)
        asm volatile("" : "+v"(pz[j][k]), "+v"(pr[j][k]), "+v"(pc[j][k]));

    float bzz[4], bzr[4], bcc[4];
    int dloc[4];
#pragma unroll
    for (int j = 0; j < 4; ++j) {
      const int col = 64 * wave + 16 * j + l15;
      bzz[j] = bz0[col]; bzr[j] = bz0[256 + col]; bcc[j] = bc0[col];
      dloc[j] = DLOC(col);
    }
    f32x4 h0s[4] = {{0,0,0,0},{0,0,0,0},{0,0,0,0},{0,0,0,0}};

    const int xrow = tid >> 4, c4 = (tid & 15) << 2;
    const float* xp = x + (size_t)(row0 + xrow) * (SEQL * 64) + c4;
    const int xbase = ((c4 >> 5) << 9) + ((((c4 >> 3) & 3) << 4) + xrow) * 8 + (c4 & 7);
    {
      float4 xv = *(const float4*)xp;
      xf[xbase] = f2bf(sanit(xv.x)); xf[xbase + 1] = f2bf(sanit(xv.y));
      xf[xbase + 2] = f2bf(sanit(xv.z)); xf[xbase + 3] = f2bf(sanit(xv.w));
    }
    __syncthreads();

    for (int ch = 0; ch < NCH; ++ch) {
      if (ch >= 2) waitge(ctr + 2, ch - 1, tid);   // B done with this slot
      unsigned short* slot = ringh + (ch & 1) * (CH * 4096);
      for (int s = 0; s < CH; ++s) {
        const int t = (ch << 3) + s;
        if (s > 0) {  // full-frame agent-coherent copy of prev step's h0
          u64* dst = (u64*)(slot + (s - 1) * 4096);
          const u64* src = (const u64*)h0f;
#pragma unroll
          for (int q = 0; q < 4; ++q) st8(dst + tid + 256 * q, src[tid + 256 * q]);
        }
        const unsigned short* xb = xf + ((t & 1) << 10);
        const bool havex = (t + 1 < SEQL);
        float4 xn;
        if (havex) xn = *(const float4*)(xp + (t + 1) * 64);

        f32x4 za[4], ra[4];
#pragma unroll
        for (int j = 0; j < 4; ++j) { za[j] = {bzz[j],bzz[j],bzz[j],bzz[j]}; ra[j] = {bzr[j],bzr[j],bzr[j],bzr[j]}; }
#pragma unroll
        for (int k = 0; k < 8; ++k) {
          bf16x8 a = *(const bf16x8*)(h0f + (k << 9) + (lane << 3));
#pragma unroll
          for (int j = 0; j < 4; ++j) { za[j] = MFMA(a, pz[j][k], za[j]); ra[j] = MFMA(a, pr[j][k], ra[j]); }
        }
#pragma unroll
        for (int k = 0; k < 2; ++k) {
          bf16x8 a = *(const bf16x8*)(xb + (k << 9) + (lane << 3));
#pragma unroll
          for (int j = 0; j < 4; ++j) {
            bf16x8 bz_ = *(const bf16x8*)(xw + ((((4 * wave + j) << 1) | k) << 9) + (lane << 3));
            bf16x8 br_ = *(const bf16x8*)(xw + ((((16 + 4 * wave + j) << 1) | k) << 9) + (lane << 3));
            za[j] = MFMA(a, bz_, za[j]); ra[j] = MFMA(a, br_, ra[j]);
          }
        }
        float zg[4][4];
#pragma unroll
        for (int j = 0; j < 4; ++j)
#pragma unroll
          for (int i = 0; i < 4; ++i) {
            zg[j][i] = sigm(za[j][i]);
            rh0f[dloc[j] + i * 8] = f2bf(sigm(ra[j][i]) * h0s[j][i]);
          }
        __syncthreads();

        f32x4 ca[4];
#pragma unroll
        for (int j = 0; j < 4; ++j) ca[j] = {bcc[j],bcc[j],bcc[j],bcc[j]};
#pragma unroll
        for (int k = 0; k < 8; ++k) {
          bf16x8 a = *(const bf16x8*)(rh0f + (k << 9) + (lane << 3));
#pragma unroll
          for (int j = 0; j < 4; ++j) ca[j] = MFMA(a, pc[j][k], ca[j]);
        }
#pragma unroll
        for (int k = 0; k < 2; ++k) {
          bf16x8 a = *(const bf16x8*)(xb + (k << 9) + (lane << 3));
#pragma unroll
          for (int j = 0; j < 4; ++j) {
            bf16x8 bc_ = *(const bf16x8*)(xw + 32768 + ((((4 * wave + j) << 1) | k) << 9) + (lane << 3));
            ca[j] = MFMA(a, bc_, ca[j]);
          }
        }
#pragma unroll
        for (int j = 0; j < 4; ++j)
#pragma unroll
          for (int i = 0; i < 4; ++i) {
            float ht = tanh_(ca[j][i]);
            float hn = h0s[j][i] + zg[j][i] * (ht - h0s[j][i]);
            h0s[j][i] = hn;
            h0f[dloc[j] + i * 8] = f2bf(hn);
          }
        if (havex) {
          unsigned short* xb1 = xf + (((t + 1) & 1) << 10);
          xb1[xbase] = f2bf(sanit(xn.x)); xb1[xbase + 1] = f2bf(sanit(xn.y));
          xb1[xbase + 2] = f2bf(sanit(xn.z)); xb1[xbase + 3] = f2bf(sanit(xn.w));
        }
        __syncthreads();
      }
      {  // final frame of the chunk
        u64* dst = (u64*)(slot + 7 * 4096);
        const u64* src = (const u64*)h0f;
#pragma unroll
        for (int q = 0; q < 4; ++q) st8(dst + tid + 256 * q, src[tid + 256 * q]);
      }
      publish(ctr + 0, ch + 1, tid);
    }
  } else if (stage == 1) {
    // ============ Stage B: layer1 h0-contribution (pure GEMM) ============
    bf16x8 p1[4][8], p2[4][8], p3[4][8];  // Wz1-z, Wz1-r, Wc1 h0-halves (kt 8..15)
#pragma unroll
    for (int j = 0; j < 4; ++j) {
      const int nt = 4 * wave + j;
#pragma unroll
      for (int k = 0; k < 8; ++k) {
        p1[j][k] = wsv[(480 + nt * 16 + 8 + k) * 64 + lane];
        p2[j][k] = wsv[(480 + (16 + nt) * 16 + 8 + k) * 64 + lane];
        p3[j][k] = wsv[(992 + nt * 16 + 8 + k) * 64 + lane];
      }
    }
#pragma unroll
    for (int j = 0; j < 4; ++j)
#pragma unroll
      for (int k = 0; k < 8; ++k)
        asm volatile("" : "+v"(p1[j][k]), "+v"(p2[j][k]), "+v"(p3[j][k]));
    float b1[4], b2[4], b3[4];
#pragma unroll
    for (int j = 0; j < 4; ++j) {
      const int col = 64 * wave + 16 * j + l15;
      b1[j] = bz1[col]; b2[j] = bz1[256 + col]; b3[j] = bc1[col];
    }
    for (int ch = 0; ch < NCH; ++ch) {
      waitge(ctr + 0, ch + 1, tid);                 // A published chunk
      if (ch >= 2) waitge(ctr + 3, ch - 1, tid);    // C done with this slot
      const unsigned short* hslot = ringh + (ch & 1) * (CH * 4096);
      unsigned short* pslot = ringp + (ch & 1) * (CH * 12288);
      for (int s = 0; s < CH; ++s) {
        const u64* fsrc = (const u64*)(hslot + s * 4096);
        u64 cq[16];
#pragma unroll
        for (int k = 0; k < 8; ++k) {
          cq[2 * k]     = ld8(fsrc + (k << 7) + (lane << 1));
          cq[2 * k + 1] = ld8(fsrc + (k << 7) + (lane << 1) + 1);
        }
        f32x4 za[4] = {{0,0,0,0},{0,0,0,0},{0,0,0,0},{0,0,0,0}};
        f32x4 ra[4] = {{0,0,0,0},{0,0,0,0},{0,0,0,0},{0,0,0,0}};
        f32x4 ca[4] = {{0,0,0,0},{0,0,0,0},{0,0,0,0},{0,0,0,0}};
#pragma unroll
        for (int k = 0; k < 8; ++k) {
          UB ub; ub.q[0] = cq[2 * k]; ub.q[1] = cq[2 * k + 1];
          bf16x8 a = ub.v;
#pragma unroll
          for (int j = 0; j < 4; ++j) {
            za[j] = MFMA(a, p1[j][k], za[j]);
            ra[j] = MFMA(a, p2[j][k], ra[j]);
            ca[j] = MFMA(a, p3[j][k], ca[j]);
          }
        }
        u64* pf = (u64*)(pslot + s * 12288);
#pragma unroll
        for (int j = 0; j < 4; ++j) {
          ushort4 vz, vr, vc;
          vz.x = f2bf(za[j][0] + b1[j]); vz.y = f2bf(za[j][1] + b1[j]);
          vz.z = f2bf(za[j][2] + b1[j]); vz.w = f2bf(za[j][3] + b1[j]);
          vr.x = f2bf(ra[j][0] + b2[j]); vr.y = f2bf(ra[j][1] + b2[j]);
          vr.z = f2bf(ra[j][2] + b2[j]); vr.w = f2bf(ra[j][3] + b2[j]);
          vc.x = f2bf(ca[j][0] + b3[j]); vc.y = f2bf(ca[j][1] + b3[j]);
          vc.z = f2bf(ca[j][2] + b3[j]); vc.w = f2bf(ca[j][3] + b3[j]);
          st8(pf + (4 * wave + j) * 64 + lane,        __builtin_bit_cast(u64, vz));
          st8(pf + (16 + 4 * wave + j) * 64 + lane,   __builtin_bit_cast(u64, vr));
          st8(pf + (32 + 4 * wave + j) * 64 + lane,   __builtin_bit_cast(u64, vc));
        }
      }
      publish(ctr + 1, ch + 1, tid);
      if (tid == 0)
        __hip_atomic_store(ctr + 2, ch + 1, __ATOMIC_RELAXED, __HIP_MEMORY_SCOPE_AGENT);
    }
  } else {
    // ============ Stage C: layer1 recurrence + LN output ============
    unsigned short* h1f  = lds;
    unsigned short* rh1f = lds + 4096;
    bf16x8 q1[4][8], q2[4][8], q3[4][8];  // h1-halves (kt 0..7)
#pragma unroll
    for (int j = 0; j < 4; ++j) {
      const int nt = 4 * wave + j;
#pragma unroll
      for (int k = 0; k < 8; ++k) {
        q1[j][k] = wsv[(480 + nt * 16 + k) * 64 + lane];
        q2[j][k] = wsv[(480 + (16 + nt) * 16 + k) * 64 + lane];
        q3[j][k] = wsv[(992 + nt * 16 + k) * 64 + lane];
      }
    }
#pragma unroll
    for (int j = 0; j < 4; ++j)
#pragma unroll
      for (int k = 0; k < 8; ++k)
        asm volatile("" : "+v"(q1[j][k]), "+v"(q2[j][k]), "+v"(q3[j][k]));
    for (int i = tid; i < 4096; i += 256) h1f[i] = 0;
    int dloc[4];
#pragma unroll
    for (int j = 0; j < 4; ++j) dloc[j] = DLOC(64 * wave + 16 * j + l15);
    f32x4 h1s[4] = {{0,0,0,0},{0,0,0,0},{0,0,0,0},{0,0,0,0}};
    __syncthreads();

    for (int ch = 0; ch < NCH; ++ch) {
      waitge(ctr + 1, ch + 1, tid);
      const unsigned short* pslot = ringp + (ch & 1) * (CH * 12288);
      for (int s = 0; s < CH; ++s) {
        const u64* pf = (const u64*)(pslot + s * 12288);
        ushort4 pz4[4], pr4[4], pc4[4];
#pragma unroll
        for (int j = 0; j < 4; ++j) {
          pz4[j] = __builtin_bit_cast(ushort4, ld8(pf + (4 * wave + j) * 64 + lane));
          pr4[j] = __builtin_bit_cast(ushort4, ld8(pf + (16 + 4 * wave + j) * 64 + lane));
          pc4[j] = __builtin_bit_cast(ushort4, ld8(pf + (32 + 4 * wave + j) * 64 + lane));
        }
        f32x4 za[4] = {{0,0,0,0},{0,0,0,0},{0,0,0,0},{0,0,0,0}};
        f32x4 ra[4] = {{0,0,0,0},{0,0,0,0},{0,0,0,0},{0,0,0,0}};
#pragma unroll
        for (int k = 0; k < 8; ++k) {
          bf16x8 a = *(const bf16x8*)(h1f + (k << 9) + (lane << 3));
#pragma unroll
          for (int j = 0; j < 4; ++j) { za[j] = MFMA(a, q1[j][k], za[j]); ra[j] = MFMA(a, q2[j][k], ra[j]); }
        }
        float zg[4][4];
        const unsigned short* pzs = (const unsigned short*)pz4;
        const unsigned short* prs = (const unsigned short*)pr4;
#pragma unroll
        for (int j = 0; j < 4; ++j)
#pragma unroll
          for (int i = 0; i < 4; ++i) {
            zg[j][i] = sigm(za[j][i] + bf2f(pzs[j * 4 + i]));
            float r = sigm(ra[j][i] + bf2f(prs[j * 4 + i]));
            rh1f[dloc[j] + i * 8] = f2bf(r * h1s[j][i]);
          }
        __syncthreads();

        f32x4 ca[4] = {{0,0,0,0},{0,0,0,0},{0,0,0,0},{0,0,0,0}};
#pragma unroll
        for (int k = 0; k < 8; ++k) {
          bf16x8 a = *(const bf16x8*)(rh1f + (k << 9) + (lane << 3));
#pragma unroll
          for (int j = 0; j < 4; ++j) ca[j] = MFMA(a, q3[j][k], ca[j]);
        }
        const unsigned short* pcs = (const unsigned short*)pc4;
#pragma unroll
        for (int j = 0; j < 4; ++j)
#pragma unroll
          for (int i = 0; i < 4; ++i) {
            float ht = tanh_(ca[j][i] + bf2f(pcs[j * 4 + i]));
            float hn = h1s[j][i] + zg[j][i] * (ht - h1s[j][i]);
            h1s[j][i] = hn;
            h1f[dloc[j] + i * 8] = f2bf(hn);
          }
        __syncthreads();
      }
      publish(ctr + 3, ch + 1, tid);
    }

    // LayerNorm from fp32 h1 state via LDS staging
    float* h1buf = (float*)lds;   // 16 x 256 fp32 = 16 KB
#pragma unroll
    for (int j = 0; j < 4; ++j)
#pragma unroll
      for (int i = 0; i < 4; ++i)
        h1buf[(quad * 4 + i) * 256 + 64 * wave + 16 * j + l15] = h1s[j][i];
    __syncthreads();

    const int r = tid >> 4, cl = tid & 15;
    float v[16], s = 0.f, sq = 0.f;
#pragma unroll
    for (int jj = 0; jj < 16; ++jj) {
      v[jj] = h1buf[r * 256 + cl + (jj << 4)];
      s += v[jj]; sq += v[jj] * v[jj];
    }
#pragma unroll
    for (int off = 8; off > 0; off >>= 1) {   // 16-lane group reduce
      s  += __shfl_xor(s, off);
      sq += __shfl_xor(sq, off);
    }
    const float mean = s * (1.f / 256.f);
    const float var  = sq * (1.f / 256.f) - mean * mean;
    const float rstd = rsqrtf(var + 1e-5f);
    float* op = out + (size_t)(row0 + r) * 256;
#pragma unroll
    for (int jj = 0; jj < 16; ++jj) {
      const int c = cl + (jj << 4);
      op[c] = (v[jj] - mean) * rstd * gamma[c] + beta[c];
    }
  }
}

extern "C" void kernel_launch(void* const* d_in, const int* in_sizes, int n_in,
                              void* d_out, int out_size, void* d_ws, size_t ws_size,
                              hipStream_t stream) {
  const float* x     = (const float*)d_in[0];
  const float* Wz0   = (const float*)d_in[1];
  const float* bz0   = (const float*)d_in[2];
  const float* Wc0   = (const float*)d_in[3];
  const float* bc0   = (const float*)d_in[4];
  const float* Wz1   = (const float*)d_in[5];
  const float* bz1   = (const float*)d_in[6];
  const float* Wc1   = (const float*)d_in[7];
  const float* bc1   = (const float*)d_in[8];
  const float* gamma = (const float*)d_in[9];
  const float* beta  = (const float*)d_in[10];
  unsigned short* ws = (unsigned short*)d_ws;
  float* out = (float*)d_out;

  hipMemsetAsync((char*)d_ws + CTRB, 0, 16 * 64, stream);
  hipLaunchKernelGGL(prep_weights, dim3(2496), dim3(256), 0, stream, Wz0, Wc0, Wz1, Wc1, ws);
  hipLaunchKernelGGL(gru_pipe, dim3(48), dim3(256), 0, stream,
                     x, bz0, bc0, bz1, bc1, gamma, beta, ws, ws, out);
}